// Round 22
// baseline (176.477 us; speedup 1.0000x reference)
//
#include <hip/hip_runtime.h>

typedef unsigned short u16;
typedef unsigned int u32;
typedef __attribute__((ext_vector_type(8))) short bf16x8;
typedef __attribute__((ext_vector_type(4))) float f32x4;

#define MFMA16(a, b, c) __builtin_amdgcn_mfma_f32_16x16x32_bf16((a), (b), (c), 0, 0, 0)

constexpr int D = 1024;       // d_model
constexpr int NH = 16;        // heads
constexpr int HD = 64;        // head dim
constexpr int BB = 4;         // batch
constexpr int SS = 2048;      // seq len
constexpr int BH = BB * NH;   // 64
constexpr int MTOK = BB * SS; // 8192
constexpr float SCALE_LOG2E = 0.125f * 1.44269504088896340736f; // HD^-0.5 * log2(e)

__device__ __forceinline__ u16 f32_bf16(float f) {
  union { float f; u32 u; } v; v.f = f;
  u32 u = v.u;
  u += 0x7FFFu + ((u >> 16) & 1u); // RNE
  return (u16)(u >> 16);
}

// single-instruction transcendental / convert paths (avoid ocml calls)
__device__ __forceinline__ float exp2_fast(float x) {
  float r; asm("v_exp_f32 %0, %1" : "=v"(r) : "v"(x)); return r;
}
__device__ __forceinline__ u16 cvt_bf16_1(float f) {
  u32 r; asm("v_cvt_pk_bf16_f32 %0, %1, %1" : "=v"(r) : "v"(f)); return (u16)r;
}
__device__ __forceinline__ u32 cvt_pk2(float lo, float hi) {
  u32 r; asm("v_cvt_pk_bf16_f32 %0, %1, %2" : "=v"(r) : "v"(lo), "v"(hi)); return r;
}

__device__ __forceinline__ void gload_lds16(const void* g, u16* l) {
  __builtin_amdgcn_global_load_lds(
      (const __attribute__((address_space(1))) u32*)g,
      (__attribute__((address_space(3))) u32*)l, 16, 0, 0);
}

// ---------------- fp32 -> bf16 elementwise convert ----------------
__global__ __launch_bounds__(256)
void cvt_bf16(const float* __restrict__ in, u16* __restrict__ out, int n4) {
  int i = blockIdx.x * 256 + threadIdx.x;
  const int stride = gridDim.x * 256;
  for (; i < n4; i += stride) {
    float4 v = reinterpret_cast<const float4*>(in)[i];
    u32 lo = (u32)f32_bf16(v.x) | ((u32)f32_bf16(v.y) << 16);
    u32 hi = (u32)f32_bf16(v.z) | ((u32)f32_bf16(v.w) << 16);
    reinterpret_cast<uint2*>(out)[i] = make_uint2(lo, hi);
  }
}

// ---------------- fp32 [R][C] -> bf16 [C][R] transpose ----------------
__global__ __launch_bounds__(256)
void transpose_bf16(const float* __restrict__ in, u16* __restrict__ out, int R, int C) {
  __shared__ float tile[32][33];
  const int c0 = blockIdx.x * 32, r0 = blockIdx.y * 32;
  const int tx = threadIdx.x, ty = threadIdx.y;
#pragma unroll
  for (int i = 0; i < 4; i++)
    tile[ty + 8 * i][tx] = in[(size_t)(r0 + ty + 8 * i) * C + c0 + tx];
  __syncthreads();
#pragma unroll
  for (int i = 0; i < 4; i++)
    out[(size_t)(c0 + ty + 8 * i) * R + r0 + tx] = f32_bf16(tile[tx][ty + 8 * i]);
}

// ---------------- QKV GEMM, 8-phase schedule (round 22) ----------------
// 256x256 tile, BK=64, 8 waves (2Mx4N -> per-wave 128x64). LDS 128KB:
// [parity][half] 32KB quarters for A and B. 4 phases per K-tile; each phase:
// {ds_read one C-quadrant's frags | stage ONE half-tile (2 gloads)} ->
// barrier -> 16 MFMA (setprio) -> barrier. Stage-ahead = 5 half-tiles
// (race-checked vs quadrant schedule: q=0..2 stage other-parity halves;
// q=3 stages A0(kt+2), last read 2 barriers earlier). Counted vmcnt(2)
// once per K-tile. Mod-8 chunk XOR swizzle: inverse-permuted global source
// (linear LDS dest) + XOR on ds_read -> 2-way = free (rule #21).
__global__ __launch_bounds__(512)
void gemm_qkv_8ph(const u16* __restrict__ A, const u16* __restrict__ Bt,
                  const float* __restrict__ bias,
                  u16* __restrict__ q_out, u16* __restrict__ k_out,
                  u16* __restrict__ vt_out) {
  constexpr int K = 1024, BK = 64, NT = K / BK; // 16
  __shared__ u16 ldsA[2][2][128 * 64]; // [parity][half][row*64+col] 16KB each
  __shared__ u16 ldsB[2][2][128 * 64];
  const int m0 = blockIdx.x * 256;
  const int n0 = blockIdx.y * 256;
  const int t = threadIdx.x, lane = t & 63, w = t >> 6;
  const int wr = w >> 2, wc = w & 3; // 2M x 4N wave grid
  const int fr = lane & 15, fq = lane >> 4;
  const int rsw = fr & 7; // read-side chunk XOR (row&7 == fr&7 for all frags)

  // staging: thread t fills LDS 16B chunk t (row=t>>3, chunk=t&7) linearly;
  // global source chunk = (t&7) ^ (row&7) so swizzled reads find chunk c.
  const int srow = t >> 3;                 // 0..63
  const int sch = (t & 7) ^ (srow & 7);
  const u16* gA0 = A + (size_t)(m0 + srow) * K + sch * 8;
  const u16* gA1 = A + (size_t)(m0 + 128 + srow) * K + sch * 8;
  const u16* gB0 = Bt + (size_t)(n0 + srow) * K + sch * 8;
  const u16* gB1 = Bt + (size_t)(n0 + 128 + srow) * K + sch * 8;

  auto stageH = [&](int H) { // half-tile H = kt*4 + h; h: 0=A0 1=A1 2=B0 3=B1
    const int kt = H >> 2, h = H & 3, par = kt & 1, ko = kt * BK;
    u16* base; const u16* src;
    if (h == 0)      { base = &ldsA[par][0][0]; src = gA0; }
    else if (h == 1) { base = &ldsA[par][1][0]; src = gA1; }
    else if (h == 2) { base = &ldsB[par][0][0]; src = gB0; }
    else             { base = &ldsB[par][1][0]; src = gB1; }
    gload_lds16(src + ko, base + t * 8);                     // rows srow
    gload_lds16(src + (size_t)64 * K + ko, base + (t + 512) * 8); // rows srow+64
  };

  f32x4 acc[8][4] = {};

  // prologue: tile 0's 4 halves + A1(1); 1 half (2 loads) stays in flight
  for (int H = 0; H < 5; ++H) stageH(H);
  asm volatile("s_waitcnt vmcnt(2)" ::: "memory");
  __builtin_amdgcn_s_barrier();
  __builtin_amdgcn_sched_barrier(0);

  bf16x8 af[4][2], bf[2][2];
  for (int kt = 0; kt < NT; ++kt) {
    const int par = kt & 1;
    const char* cA = (const char*)&ldsA[par][wr][0];        // wave's A half
    const char* cB = (const char*)&ldsB[par][wc >> 1][0];   // wave's B half
    const int brow = (wc & 1) * 64;
#pragma unroll
    for (int q = 0; q < 4; ++q) {
      const int mi = q >> 1, nj = q & 1;
      if (nj == 0) {
#pragma unroll
        for (int i = 0; i < 4; i++)
#pragma unroll
          for (int ks = 0; ks < 2; ks++)
            af[i][ks] = *reinterpret_cast<const bf16x8*>(
                cA + ((mi * 4 + i) * 16 + fr) * 128 + (((ks * 4 + fq) ^ rsw) << 4));
      }
#pragma unroll
      for (int j = 0; j < 2; j++)
#pragma unroll
        for (int ks = 0; ks < 2; ks++)
          bf[j][ks] = *reinterpret_cast<const bf16x8*>(
              cB + (brow + (nj * 2 + j) * 16 + fr) * 128 + (((ks * 4 + fq) ^ rsw) << 4));
      const int H = kt * 4 + q + 5;
      if (H < NT * 4) stageH(H);
      __builtin_amdgcn_s_barrier();
      __builtin_amdgcn_sched_barrier(0);
      __builtin_amdgcn_s_setprio(1);
#pragma unroll
      for (int i = 0; i < 4; i++)
#pragma unroll
        for (int j = 0; j < 2; j++)
#pragma unroll
          for (int ks = 0; ks < 2; ks++)
            acc[mi * 4 + i][nj * 2 + j] =
                MFMA16(af[i][ks], bf[j][ks], acc[mi * 4 + i][nj * 2 + j]);
      __builtin_amdgcn_s_setprio(0);
      if (q == 3) { // end of K-tile: ensure tile kt+1's halves landed
        if (kt + 2 < NT)
          asm volatile("s_waitcnt vmcnt(2)" ::: "memory");
        else if (kt + 1 < NT)
          asm volatile("s_waitcnt vmcnt(0)" ::: "memory");
      }
      __builtin_amdgcn_s_barrier();
      __builtin_amdgcn_sched_barrier(0);
    }
  }

  // epilogue (r17-verified 8x4 scatter; `which` is block-uniform: 256 | 1024)
  const int swhich = n0 >> 10;
#pragma unroll
  for (int i = 0; i < 8; i++) {
#pragma unroll
    for (int j = 0; j < 4; j++) {
      const int ncol = n0 + wc * 64 + j * 16 + fr;
      const float bs = bias[ncol];
      const int rem = ncol & 1023;
      const int hh = rem >> 6, dd = rem & 63;
      const int mbase = m0 + wr * 128 + i * 16 + fq * 4;
      const int bb = mbase >> 11, ss = mbase & 2047;
      const int bh = bb * 16 + hh;
      if (swhich == 0) {
#pragma unroll
        for (int r = 0; r < 4; r++)
          q_out[((size_t)bh * SS + ss + r) * HD + dd] =
              f32_bf16((acc[i][j][r] + bs) * SCALE_LOG2E);
      } else if (swhich == 1) {
#pragma unroll
        for (int r = 0; r < 4; r++)
          k_out[((size_t)bh * SS + ss + r) * HD + dd] = f32_bf16(acc[i][j][r] + bs);
      } else {
        const u32 p01 = cvt_pk2(acc[i][j][0] + bs, acc[i][j][1] + bs);
        const u32 p23 = cvt_pk2(acc[i][j][2] + bs, acc[i][j][3] + bs);
        *reinterpret_cast<uint2*>(&vt_out[((size_t)bh * HD + dd) * SS + ss]) =
            make_uint2(p01, p23);
      }
    }
  }
}

// ---------------- bf16 GEMM (r13 config, used for the output projection) ----
template <int MODE>
__global__ __launch_bounds__(256)
void gemm_bf16(const u16* __restrict__ A, const u16* __restrict__ Bt,
               const float* __restrict__ bias,
               u16* __restrict__ q_out, u16* __restrict__ k_out,
               u16* __restrict__ vt_out, float* __restrict__ f_out,
               int M, int N, int K) {
  constexpr int BK = 32;
  __shared__ u16 lds_a[3][128 * BK];
  __shared__ u16 lds_b[3][128 * BK];
  const int m0 = blockIdx.x * 128;
  const int n0 = blockIdx.y * 128;
  const int t = threadIdx.x;
  const int lane = t & 63;
  const int w = t >> 6;
  const int wr = w >> 1, wc = w & 1;        // 2x2 wave grid, 64x64 per wave
  const int fr = lane & 15, fq = lane >> 4; // fragment row/col group

  const int srow = t >> 2;
  const int schunk = (t & 3) ^ ((srow >> 1) & 3);
  const u16* ga0 = A + (size_t)(m0 + srow) * K + schunk * 8;
  const u16* ga1 = ga0 + (size_t)64 * K;
  const u16* gb0 = Bt + (size_t)(n0 + srow) * K + schunk * 8;
  const u16* gb1 = gb0 + (size_t)64 * K;

  const int swz = ((fr >> 1) & 3) << 4;

#define GSTAGE(bufi, koff)                                                    \
  {                                                                           \
    gload_lds16(ga0 + (koff), lds_a[bufi] + t * 8);                           \
    gload_lds16(ga1 + (koff), lds_a[bufi] + (t + 256) * 8);                   \
    gload_lds16(gb0 + (koff), lds_b[bufi] + t * 8);                           \
    gload_lds16(gb1 + (koff), lds_b[bufi] + (t + 256) * 8);                   \
  }

  f32x4 acc[4][4] = {};
  const int nt = K / BK;

  GSTAGE(0, 0);
  GSTAGE(1, BK);

  int cur = 0;
  for (int kt = 0; kt < nt; ++kt) {
    if (kt + 1 < nt)
      asm volatile("s_waitcnt vmcnt(4)" ::: "memory");
    else
      asm volatile("s_waitcnt vmcnt(0)" ::: "memory");
    __builtin_amdgcn_s_barrier();
    __builtin_amdgcn_sched_barrier(0);

    const char* ca = (const char*)lds_a[cur];
    const char* cb = (const char*)lds_b[cur];
    bf16x8 af[4], bfr[4];
#pragma unroll
    for (int i = 0; i < 4; i++)
      af[i] = *reinterpret_cast<const bf16x8*>(
          ca + (wr * 64 + i * 16 + fr) * 64 + ((fq * 16) ^ swz));
#pragma unroll
    for (int i = 0; i < 4; i++)
      bfr[i] = *reinterpret_cast<const bf16x8*>(
          cb + (wc * 64 + i * 16 + fr) * 64 + ((fq * 16) ^ swz));
    __builtin_amdgcn_s_setprio(1);
#pragma unroll
    for (int i = 0; i < 4; i++)
#pragma unroll
      for (int j = 0; j < 4; j++)
        acc[i][j] = MFMA16(af[i], bfr[j], acc[i][j]);
    __builtin_amdgcn_s_setprio(0);

    if (kt + 2 < nt) {
      const int bufn = cur >= 1 ? cur - 1 : 2; // (cur+2)%3
      GSTAGE(bufn, (kt + 2) * BK);
    }
    cur = cur == 2 ? 0 : cur + 1;
  }
#undef GSTAGE

#pragma unroll
  for (int i = 0; i < 4; i++) {
#pragma unroll
    for (int j = 0; j < 4; j++) {
      const int ncol = n0 + wc * 64 + j * 16 + fr;
      const float bs = bias[ncol];
#pragma unroll
      for (int r = 0; r < 4; r++) {
        const int mrow = m0 + wr * 64 + i * 16 + fq * 4 + r;
        const float vv = acc[i][j][r] + bs;
        if (MODE == 0) {
          const int which = ncol >> 10;
          const int rem = ncol & 1023;
          const int hh = rem >> 6, dd = rem & 63;
          const int bb = mrow >> 11, ss = mrow & 2047;
          const int bh = bb * 16 + hh;
          if (which == 0)
            q_out[((size_t)bh * SS + ss) * HD + dd] = f32_bf16(vv * SCALE_LOG2E);
          else if (which == 1)
            k_out[((size_t)bh * SS + ss) * HD + dd] = f32_bf16(vv);
          else
            vt_out[((size_t)bh * HD + dd) * SS + ss] = f32_bf16(vv);
        } else {
          f_out[(size_t)mrow * N + ncol] = vv;
        }
      }
    }
  }
}

// ---------------- causal flash attention ----------------
// Q (pre-scaled), K: [BH][S][64] bf16 ; Vt: [BH][64][S] bf16 ; vals: [B][S][D] bf16
// QBLK=128, 8 waves/block; block = q-tile pair (pA, 15-pA), uniform 34 kv iters;
// XCD swizzle (8 heads/XCD, L2-resident); 3-buffer ring + counted vmcnt;
// swapped QK^T (S^T = mfma(K,Q)) -> scalar softmax state per lane (round 13).
__global__ __launch_bounds__(512)
void attn_fwd(const u16* __restrict__ Qb, const u16* __restrict__ Kb,
              const u16* __restrict__ Vt, u16* __restrict__ vals) {
  const int bid = blockIdx.x;                 // 0..511
  const int wk = (bid & 7) * 64 + (bid >> 3); // XCD-contiguous chunks of 64
  const int bh = wk >> 3;                     // 8 heads per XCD chunk
  const int pA = wk & 7;
  const int qtA = pA, qtB = 15 - pA;          // 128-row q-tiles
  const int nA = 2 * qtA + 2;                 // kv tiles for segment A
  const int nTot = 34;                        // nA + 2*qtB+2 == 34 uniform
  const u16* Qp = Qb + (size_t)bh * SS * HD;
  const char* Kp = (const char*)(Kb + (size_t)bh * SS * HD);
  const char* Vp = (const char*)(Vt + (size_t)bh * HD * SS);
  const int t = threadIdx.x, lane = t & 63, w = t >> 6; // w 0..7
  const int fr = lane & 15, fq = lane >> 4;
  const int swz = (fr & 7) << 4;

  __shared__ u16 kbuf[3][4096]; // [64 kv-rows][128B] swizzled, 8KB each
  __shared__ u16 vbuf[3][4096]; // [64 d-rows][128B keys] swizzled
  __shared__ u16 plds[8][16][72];
  u16* myp = &plds[w][0][0];

  const int lin = t * 16; // staging byte offset: 512 thr x 16B = 8KB tile

  int offKV[8];
#pragma unroll
  for (int kf = 0; kf < 4; kf++)
#pragma unroll
    for (int kk = 0; kk < 2; kk++)
      offKV[kf * 2 + kk] = (kf * 16 + fr) * 128 + ((kk * 64 + fq * 16) ^ swz);

  bf16x8 aq[2];
  {
    const int qbase = qtA * 128 + w * 16;
#pragma unroll
    for (int kk = 0; kk < 2; kk++)
      aq[kk] = *reinterpret_cast<const bf16x8*>(Qp + (size_t)(qbase + fr) * HD + kk * 32 + fq * 8);
  }

  f32x4 o[4] = {};
  float mrun = -3e38f, lpart = 0.f; // scalars: this lane's q = w*16 + fr

#define STAGE(bufi, kvt_)                                                     \
  {                                                                           \
    const int row = lin >> 7, colb = lin & 127;                               \
    const int scol = colb ^ ((row & 7) << 4);                                 \
    gload_lds16(Kp + (size_t)((kvt_) * 64 + row) * 128 + scol,                \
                &kbuf[bufi][lin >> 1]);                                       \
    gload_lds16(Vp + (size_t)row * 4096 + (kvt_) * 128 + scol,                \
                &vbuf[bufi][lin >> 1]);                                       \
  }
#define KVIDX(ti_) ((ti_) >= nA ? (ti_) - nA : (ti_))

  auto write_out = [&](int qt) {
    const int b_ = bh >> 4, h_ = bh & 15;
    const int qb = qt * 128 + w * 16;
    float rs = lpart;
    rs += __shfl_xor(rs, 16, 64);
    rs += __shfl_xor(rs, 32, 64);
    const float linv = 1.f / rs;
    float lj[4];
#pragma unroll
    for (int j = 0; j < 4; j++)
      lj[j] = __shfl(linv, (lane & 48) + fq * 4 + j, 64);
#pragma unroll
    for (int df = 0; df < 4; df++)
#pragma unroll
      for (int j = 0; j < 4; j++) {
        const float vv = o[df][j] * lj[j];
        const int qg = qb + fq * 4 + j;
        vals[((size_t)(b_ * SS + qg)) * D + h_ * HD + df * 16 + fr] = cvt_bf16_1(vv);
      }
  };

  int cur = 0;
  STAGE(0, 0);
  STAGE(1, 1); // nA >= 2 always, so kv tile 1 of segment A is correct

  for (int ti = 0; ti < nTot; ++ti) {
    const bool segB = ti >= nA;
    const int kvt = segB ? ti - nA : ti;
    const int qt = segB ? qtB : qtA;

    if (ti + 1 < nTot)
      asm volatile("s_waitcnt vmcnt(2)" ::: "memory");
    else
      asm volatile("s_waitcnt vmcnt(0)" ::: "memory");
    __builtin_amdgcn_s_barrier();
    __builtin_amdgcn_sched_barrier(0);

    if (ti == nA) { // segment switch: flush A, reset state for B
      write_out(qtA);
      const int qbase = qtB * 128 + w * 16;
#pragma unroll
      for (int kk = 0; kk < 2; kk++)
        aq[kk] = *reinterpret_cast<const bf16x8*>(Qp + (size_t)(qbase + fr) * HD + kk * 32 + fq * 8);
      mrun = -3e38f; lpart = 0.f;
#pragma unroll
      for (int df = 0; df < 4; df++) o[df] = f32x4{0.f, 0.f, 0.f, 0.f};
    }

    const char* kb = (const char*)kbuf[cur];
    const char* vb = (const char*)vbuf[cur];

    // S^T = K Q^T: sc[kf][j] = S[q = w*16+fr][key = kvt*64 + kf*16 + fq*4 + j]
    f32x4 sc[4] = {};
    __builtin_amdgcn_s_setprio(1);
#pragma unroll
    for (int kf = 0; kf < 4; kf++) {
#pragma unroll
      for (int kk = 0; kk < 2; kk++) {
        bf16x8 bk = *reinterpret_cast<const bf16x8*>(kb + offKV[kf * 2 + kk]);
        sc[kf] = MFMA16(bk, aq[kk], sc[kf]); // swapped operands -> S^T
      }
    }
    __builtin_amdgcn_s_setprio(0);
    // causal mask: the two kv tiles straddling this q-tile's diagonal
    if ((kvt >> 1) == qt) {
      const int qg = qt * 128 + w * 16 + fr;
      const int kg0 = kvt * 64 + fq * 4;
#pragma unroll
      for (int kf = 0; kf < 4; kf++)
#pragma unroll
        for (int j = 0; j < 4; j++)
          if (kg0 + kf * 16 + j > qg) sc[kf][j] = -3e38f;
    }
    // row max: in-lane over 16 regs, then reduce across the 4 fq groups
    float m = fmaxf(fmaxf(sc[0][0], sc[0][1]), fmaxf(sc[0][2], sc[0][3]));
#pragma unroll
    for (int kf = 1; kf < 4; kf++)
      m = fmaxf(m, fmaxf(fmaxf(sc[kf][0], sc[kf][1]), fmaxf(sc[kf][2], sc[kf][3])));
    m = fmaxf(m, __shfl_xor(m, 16, 64));
    m = fmaxf(m, __shfl_xor(m, 32, 64));
    // defer-max: rescale only when the max grew by > 8 (log2 units)
    if (__any((int)(m > mrun + 8.f))) {
      const float mnew = fmaxf(mrun, m);
      const float alpha = exp2_fast(mrun - mnew);
      mrun = mnew;
      lpart *= alpha;
      float aj[4];
#pragma unroll
      for (int j = 0; j < 4; j++)
        aj[j] = __shfl(alpha, (lane & 48) + fq * 4 + j, 64);
#pragma unroll
      for (int df = 0; df < 4; df++)
#pragma unroll
        for (int j = 0; j < 4; j++) o[df][j] *= aj[j];
    }
    // P = exp2(S - mrun); per-lane partial row sum (reduced at flush)
#pragma unroll
    for (int kf = 0; kf < 4; kf++)
#pragma unroll
      for (int j = 0; j < 4; j++) {
        const float p = exp2_fast(sc[kf][j] - mrun);
        sc[kf][j] = p;
        lpart += p;
      }
    // P^T -> LDS [q][key] via packed bf16 pairs (keys consecutive)
    {
      u16* mypr = myp + fr * 72;
#pragma unroll
      for (int kf = 0; kf < 4; kf++) {
        const u32 p01 = cvt_pk2(sc[kf][0], sc[kf][1]);
        const u32 p23 = cvt_pk2(sc[kf][2], sc[kf][3]);
        *reinterpret_cast<u32*>(mypr + kf * 16 + fq * 4) = p01;
        *reinterpret_cast<u32*>(mypr + kf * 16 + fq * 4 + 2) = p23;
      }
    }
    bf16x8 pa[2];
#pragma unroll
    for (int kk = 0; kk < 2; kk++)
      pa[kk] = *reinterpret_cast<const bf16x8*>(myp + fr * 72 + kk * 32 + fq * 8);
    // O += P V  (unchanged: A = P rows from LDS, B = Vt tile)
    __builtin_amdgcn_s_setprio(1);
#pragma unroll
    for (int df = 0; df < 4; df++) {
#pragma unroll
      for (int kk = 0; kk < 2; kk++) {
        bf16x8 bv = *reinterpret_cast<const bf16x8*>(vb + offKV[df * 2 + kk]);
        o[df] = MFMA16(pa[kk], bv, o[df]);
      }
    }
    __builtin_amdgcn_s_setprio(0);

    const int nxt = ti + 2;
    if (nxt < nTot) {
      const int bufn = cur >= 1 ? cur - 1 : 2; // (cur+2)%3
      STAGE(bufn, KVIDX(nxt));
    }
    cur = cur == 2 ? 0 : cur + 1;
  }
  write_out(qtB);
#undef STAGE
#undef KVIDX
}

extern "C" void kernel_launch(void* const* d_in, const int* in_sizes, int n_in,
                              void* d_out, int out_size, void* d_ws, size_t ws_size,
                              hipStream_t stream) {
  const float* x = (const float*)d_in[0];
  const float* Wqkv = (const float*)d_in[1];
  const float* bqkv = (const float*)d_in[2];
  const float* Wout = (const float*)d_in[3];
  const float* bout = (const float*)d_in[4];
  float* out = (float*)d_out;

  char* p = (char*)d_ws;
  u16* xb = (u16*)p;    p += (size_t)MTOK * D * 2;       // 16.8 MB
  u16* wqkvT = (u16*)p; p += (size_t)3 * D * D * 2;      // 6.3 MB
  u16* woutT = (u16*)p; p += (size_t)D * D * 2;          // 2.1 MB
  u16* Qb = (u16*)p;    p += (size_t)BH * SS * HD * 2;   // 16.8 MB
  u16* Kb = (u16*)p;    p += (size_t)BH * SS * HD * 2;   // 16.8 MB
  u16* Vt = (u16*)p;    p += (size_t)BH * SS * HD * 2;   // 16.8 MB
  u16* vals = (u16*)p;  p += (size_t)MTOK * D * 2;       // 16.8 MB  (total ~92 MB)

  cvt_bf16<<<2048, 256, 0, stream>>>(x, xb, MTOK * D / 4);
  transpose_bf16<<<dim3(3 * D / 32, D / 32), dim3(32, 8), 0, stream>>>(Wqkv, wqkvT, D, 3 * D);
  transpose_bf16<<<dim3(D / 32, D / 32), dim3(32, 8), 0, stream>>>(Wout, woutT, D, D);
  gemm_qkv_8ph<<<dim3(MTOK / 256, 3 * D / 256), 512, 0, stream>>>(
      xb, wqkvT, bqkv, Qb, Kb, Vt);
  attn_fwd<<<dim3(512), 512, 0, stream>>>(Qb, Kb, Vt, vals);
  gemm_bf16<1><<<dim3(MTOK / 128, D / 128), 256, 0, stream>>>(
      vals, woutT, bout, nullptr, nullptr, nullptr, out, MTOK, D, D);
}

// Round 23
// 171.645 us; speedup vs baseline: 1.0282x; 1.0282x over previous
//
#include <hip/hip_runtime.h>

typedef unsigned short u16;
typedef unsigned int u32;
typedef __attribute__((ext_vector_type(8))) short bf16x8;
typedef __attribute__((ext_vector_type(4))) float f32x4;

#define MFMA16(a, b, c) __builtin_amdgcn_mfma_f32_16x16x32_bf16((a), (b), (c), 0, 0, 0)

constexpr int D = 1024;       // d_model
constexpr int NH = 16;        // heads
constexpr int HD = 64;        // head dim
constexpr int BB = 4;         // batch
constexpr int SS = 2048;      // seq len
constexpr int BH = BB * NH;   // 64
constexpr int MTOK = BB * SS; // 8192
constexpr float SCALE_LOG2E = 0.125f * 1.44269504088896340736f; // HD^-0.5 * log2(e)

__device__ __forceinline__ u16 f32_bf16(float f) {
  union { float f; u32 u; } v; v.f = f;
  u32 u = v.u;
  u += 0x7FFFu + ((u >> 16) & 1u); // RNE
  return (u16)(u >> 16);
}

// single-instruction transcendental / convert paths (avoid ocml calls)
__device__ __forceinline__ float exp2_fast(float x) {
  float r; asm("v_exp_f32 %0, %1" : "=v"(r) : "v"(x)); return r;
}
__device__ __forceinline__ u16 cvt_bf16_1(float f) {
  u32 r; asm("v_cvt_pk_bf16_f32 %0, %1, %1" : "=v"(r) : "v"(f)); return (u16)r;
}
__device__ __forceinline__ u32 cvt_pk2(float lo, float hi) {
  u32 r; asm("v_cvt_pk_bf16_f32 %0, %1, %2" : "=v"(r) : "v"(lo), "v"(hi)); return r;
}

__device__ __forceinline__ void gload_lds16(const void* g, u16* l) {
  __builtin_amdgcn_global_load_lds(
      (const __attribute__((address_space(1))) u32*)g,
      (__attribute__((address_space(3))) u32*)l, 16, 0, 0);
}

// ---------------- fp32 -> bf16 elementwise convert ----------------
__global__ __launch_bounds__(256)
void cvt_bf16(const float* __restrict__ in, u16* __restrict__ out, int n4) {
  int i = blockIdx.x * 256 + threadIdx.x;
  const int stride = gridDim.x * 256;
  for (; i < n4; i += stride) {
    float4 v = reinterpret_cast<const float4*>(in)[i];
    u32 lo = (u32)f32_bf16(v.x) | ((u32)f32_bf16(v.y) << 16);
    u32 hi = (u32)f32_bf16(v.z) | ((u32)f32_bf16(v.w) << 16);
    reinterpret_cast<uint2*>(out)[i] = make_uint2(lo, hi);
  }
}

// ---------------- fp32 [R][C] -> bf16 [C][R] transpose ----------------
__global__ __launch_bounds__(256)
void transpose_bf16(const float* __restrict__ in, u16* __restrict__ out, int R, int C) {
  __shared__ float tile[32][33];
  const int c0 = blockIdx.x * 32, r0 = blockIdx.y * 32;
  const int tx = threadIdx.x, ty = threadIdx.y;
#pragma unroll
  for (int i = 0; i < 4; i++)
    tile[ty + 8 * i][tx] = in[(size_t)(r0 + ty + 8 * i) * C + c0 + tx];
  __syncthreads();
#pragma unroll
  for (int i = 0; i < 4; i++)
    out[(size_t)(c0 + ty + 8 * i) * R + r0 + tx] = f32_bf16(tile[tx][ty + 8 * i]);
}

// ---------------- bf16 GEMM: C[M][N] = A[M][K] * Bt[N][K]^T + bias ----------------
// Round-13 configuration -- best measured total (171.7us, reproduced twice).
// r15 (B-direct regs), r16 (2x MFMA/barrier), r17 (256x256 tile), r22
// (8-phase port) all null or negative: structure jointly limited by LDS pipe
// + lockstep waits; breaking past needs the full derived-waits co-designed
// schedule (m201 template), out of scope for this harness loop.
// 2D grid. T2 LDS swizzle (BANK_CONFLICT 6.3M -> 0). 3-buffer ring,
// 2-tile-deep prefetch, counted vmcnt(4), one barrier per K-step.
// MODE 0: scatter into Q (pre-scaled by SCALE*log2e) [BH][S][64], K [BH][S][64],
//         Vt [BH][64][S] (bf16)
// MODE 1: fp32 out [M][N]
template <int MODE>
__global__ __launch_bounds__(256)
void gemm_bf16(const u16* __restrict__ A, const u16* __restrict__ Bt,
               const float* __restrict__ bias,
               u16* __restrict__ q_out, u16* __restrict__ k_out,
               u16* __restrict__ vt_out, float* __restrict__ f_out,
               int M, int N, int K) {
  constexpr int BK = 32;
  __shared__ u16 lds_a[3][128 * BK];
  __shared__ u16 lds_b[3][128 * BK];
  const int m0 = blockIdx.x * 128;
  const int n0 = blockIdx.y * 128;
  const int t = threadIdx.x;
  const int lane = t & 63;
  const int w = t >> 6;
  const int wr = w >> 1, wc = w & 1;        // 2x2 wave grid, 64x64 per wave
  const int fr = lane & 15, fq = lane >> 4; // fragment row/col group

  const int srow = t >> 2;
  const int schunk = (t & 3) ^ ((srow >> 1) & 3);
  const u16* ga0 = A + (size_t)(m0 + srow) * K + schunk * 8;
  const u16* ga1 = ga0 + (size_t)64 * K;
  const u16* gb0 = Bt + (size_t)(n0 + srow) * K + schunk * 8;
  const u16* gb1 = gb0 + (size_t)64 * K;

  const int swz = ((fr >> 1) & 3) << 4;

#define GSTAGE(bufi, koff)                                                    \
  {                                                                           \
    gload_lds16(ga0 + (koff), lds_a[bufi] + t * 8);                           \
    gload_lds16(ga1 + (koff), lds_a[bufi] + (t + 256) * 8);                   \
    gload_lds16(gb0 + (koff), lds_b[bufi] + t * 8);                           \
    gload_lds16(gb1 + (koff), lds_b[bufi] + (t + 256) * 8);                   \
  }

  f32x4 acc[4][4] = {};
  const int nt = K / BK;

  GSTAGE(0, 0);
  GSTAGE(1, BK);

  int cur = 0;
  for (int kt = 0; kt < nt; ++kt) {
    if (kt + 1 < nt)
      asm volatile("s_waitcnt vmcnt(4)" ::: "memory");
    else
      asm volatile("s_waitcnt vmcnt(0)" ::: "memory");
    __builtin_amdgcn_s_barrier();
    __builtin_amdgcn_sched_barrier(0);

    const char* ca = (const char*)lds_a[cur];
    const char* cb = (const char*)lds_b[cur];
    bf16x8 af[4], bfr[4];
#pragma unroll
    for (int i = 0; i < 4; i++)
      af[i] = *reinterpret_cast<const bf16x8*>(
          ca + (wr * 64 + i * 16 + fr) * 64 + ((fq * 16) ^ swz));
#pragma unroll
    for (int i = 0; i < 4; i++)
      bfr[i] = *reinterpret_cast<const bf16x8*>(
          cb + (wc * 64 + i * 16 + fr) * 64 + ((fq * 16) ^ swz));
    __builtin_amdgcn_s_setprio(1);
#pragma unroll
    for (int i = 0; i < 4; i++)
#pragma unroll
      for (int j = 0; j < 4; j++)
        acc[i][j] = MFMA16(af[i], bfr[j], acc[i][j]);
    __builtin_amdgcn_s_setprio(0);

    if (kt + 2 < nt) {
      const int bufn = cur >= 1 ? cur - 1 : 2; // (cur+2)%3
      GSTAGE(bufn, (kt + 2) * BK);
    }
    cur = cur == 2 ? 0 : cur + 1;
  }
#undef GSTAGE

#pragma unroll
  for (int i = 0; i < 4; i++) {
#pragma unroll
    for (int j = 0; j < 4; j++) {
      const int ncol = n0 + wc * 64 + j * 16 + fr;
      const float bs = bias[ncol];
#pragma unroll
      for (int r = 0; r < 4; r++) {
        const int mrow = m0 + wr * 64 + i * 16 + fq * 4 + r;
        const float vv = acc[i][j][r] + bs;
        if (MODE == 0) {
          const int which = ncol >> 10;
          const int rem = ncol & 1023;
          const int hh = rem >> 6, dd = rem & 63;
          const int bb = mrow >> 11, ss = mrow & 2047;
          const int bh = bb * 16 + hh;
          if (which == 0)
            q_out[((size_t)bh * SS + ss) * HD + dd] = f32_bf16(vv * SCALE_LOG2E);
          else if (which == 1)
            k_out[((size_t)bh * SS + ss) * HD + dd] = f32_bf16(vv);
          else
            vt_out[((size_t)bh * HD + dd) * SS + ss] = f32_bf16(vv);
        } else {
          f_out[(size_t)mrow * N + ncol] = vv;
        }
      }
    }
  }
}

// ---------------- causal flash attention ----------------
// Q (pre-scaled), K: [BH][S][64] bf16 ; Vt: [BH][64][S] bf16 ; vals: [B][S][D] bf16
// QBLK=128, 8 waves/block; block = q-tile pair (pA, 15-pA), uniform 34 kv iters;
// XCD swizzle (8 heads/XCD, L2-resident); 3-buffer ring + counted vmcnt;
// swapped QK^T (S^T = mfma(K,Q)) -> scalar softmax state per lane (round 13).
__global__ __launch_bounds__(512)
void attn_fwd(const u16* __restrict__ Qb, const u16* __restrict__ Kb,
              const u16* __restrict__ Vt, u16* __restrict__ vals) {
  const int bid = blockIdx.x;                 // 0..511
  const int wk = (bid & 7) * 64 + (bid >> 3); // XCD-contiguous chunks of 64
  const int bh = wk >> 3;                     // 8 heads per XCD chunk
  const int pA = wk & 7;
  const int qtA = pA, qtB = 15 - pA;          // 128-row q-tiles
  const int nA = 2 * qtA + 2;                 // kv tiles for segment A
  const int nTot = 34;                        // nA + 2*qtB+2 == 34 uniform
  const u16* Qp = Qb + (size_t)bh * SS * HD;
  const char* Kp = (const char*)(Kb + (size_t)bh * SS * HD);
  const char* Vp = (const char*)(Vt + (size_t)bh * HD * SS);
  const int t = threadIdx.x, lane = t & 63, w = t >> 6; // w 0..7
  const int fr = lane & 15, fq = lane >> 4;
  const int swz = (fr & 7) << 4;

  __shared__ u16 kbuf[3][4096]; // [64 kv-rows][128B] swizzled, 8KB each
  __shared__ u16 vbuf[3][4096]; // [64 d-rows][128B keys] swizzled
  __shared__ u16 plds[8][16][72];
  u16* myp = &plds[w][0][0];

  const int lin = t * 16; // staging byte offset: 512 thr x 16B = 8KB tile

  int offKV[8];
#pragma unroll
  for (int kf = 0; kf < 4; kf++)
#pragma unroll
    for (int kk = 0; kk < 2; kk++)
      offKV[kf * 2 + kk] = (kf * 16 + fr) * 128 + ((kk * 64 + fq * 16) ^ swz);

  bf16x8 aq[2];
  {
    const int qbase = qtA * 128 + w * 16;
#pragma unroll
    for (int kk = 0; kk < 2; kk++)
      aq[kk] = *reinterpret_cast<const bf16x8*>(Qp + (size_t)(qbase + fr) * HD + kk * 32 + fq * 8);
  }

  f32x4 o[4] = {};
  float mrun = -3e38f, lpart = 0.f; // scalars: this lane's q = w*16 + fr

#define STAGE(bufi, kvt_)                                                     \
  {                                                                           \
    const int row = lin >> 7, colb = lin & 127;                               \
    const int scol = colb ^ ((row & 7) << 4);                                 \
    gload_lds16(Kp + (size_t)((kvt_) * 64 + row) * 128 + scol,                \
                &kbuf[bufi][lin >> 1]);                                       \
    gload_lds16(Vp + (size_t)row * 4096 + (kvt_) * 128 + scol,                \
                &vbuf[bufi][lin >> 1]);                                       \
  }
#define KVIDX(ti_) ((ti_) >= nA ? (ti_) - nA : (ti_))

  auto write_out = [&](int qt) {
    const int b_ = bh >> 4, h_ = bh & 15;
    const int qb = qt * 128 + w * 16;
    float rs = lpart;
    rs += __shfl_xor(rs, 16, 64);
    rs += __shfl_xor(rs, 32, 64);
    const float linv = 1.f / rs;
    float lj[4];
#pragma unroll
    for (int j = 0; j < 4; j++)
      lj[j] = __shfl(linv, (lane & 48) + fq * 4 + j, 64);
#pragma unroll
    for (int df = 0; df < 4; df++)
#pragma unroll
      for (int j = 0; j < 4; j++) {
        const float vv = o[df][j] * lj[j];
        const int qg = qb + fq * 4 + j;
        vals[((size_t)(b_ * SS + qg)) * D + h_ * HD + df * 16 + fr] = cvt_bf16_1(vv);
      }
  };

  int cur = 0;
  STAGE(0, 0);
  STAGE(1, 1); // nA >= 2 always, so kv tile 1 of segment A is correct

  for (int ti = 0; ti < nTot; ++ti) {
    const bool segB = ti >= nA;
    const int kvt = segB ? ti - nA : ti;
    const int qt = segB ? qtB : qtA;

    if (ti + 1 < nTot)
      asm volatile("s_waitcnt vmcnt(2)" ::: "memory");
    else
      asm volatile("s_waitcnt vmcnt(0)" ::: "memory");
    __builtin_amdgcn_s_barrier();
    __builtin_amdgcn_sched_barrier(0);

    if (ti == nA) { // segment switch: flush A, reset state for B
      write_out(qtA);
      const int qbase = qtB * 128 + w * 16;
#pragma unroll
      for (int kk = 0; kk < 2; kk++)
        aq[kk] = *reinterpret_cast<const bf16x8*>(Qp + (size_t)(qbase + fr) * HD + kk * 32 + fq * 8);
      mrun = -3e38f; lpart = 0.f;
#pragma unroll
      for (int df = 0; df < 4; df++) o[df] = f32x4{0.f, 0.f, 0.f, 0.f};
    }

    const char* kb = (const char*)kbuf[cur];
    const char* vb = (const char*)vbuf[cur];

    // S^T = K Q^T: sc[kf][j] = S[q = w*16+fr][key = kvt*64 + kf*16 + fq*4 + j]
    f32x4 sc[4] = {};
    __builtin_amdgcn_s_setprio(1);
#pragma unroll
    for (int kf = 0; kf < 4; kf++) {
#pragma unroll
      for (int kk = 0; kk < 2; kk++) {
        bf16x8 bk = *reinterpret_cast<const bf16x8*>(kb + offKV[kf * 2 + kk]);
        sc[kf] = MFMA16(bk, aq[kk], sc[kf]); // swapped operands -> S^T
      }
    }
    __builtin_amdgcn_s_setprio(0);
    // causal mask: the two kv tiles straddling this q-tile's diagonal
    if ((kvt >> 1) == qt) {
      const int qg = qt * 128 + w * 16 + fr;
      const int kg0 = kvt * 64 + fq * 4;
#pragma unroll
      for (int kf = 0; kf < 4; kf++)
#pragma unroll
        for (int j = 0; j < 4; j++)
          if (kg0 + kf * 16 + j > qg) sc[kf][j] = -3e38f;
    }
    // row max: in-lane over 16 regs, then reduce across the 4 fq groups
    float m = fmaxf(fmaxf(sc[0][0], sc[0][1]), fmaxf(sc[0][2], sc[0][3]));
#pragma unroll
    for (int kf = 1; kf < 4; kf++)
      m = fmaxf(m, fmaxf(fmaxf(sc[kf][0], sc[kf][1]), fmaxf(sc[kf][2], sc[kf][3])));
    m = fmaxf(m, __shfl_xor(m, 16, 64));
    m = fmaxf(m, __shfl_xor(m, 32, 64));
    // defer-max: rescale only when the max grew by > 8 (log2 units)
    if (__any((int)(m > mrun + 8.f))) {
      const float mnew = fmaxf(mrun, m);
      const float alpha = exp2_fast(mrun - mnew);
      mrun = mnew;
      lpart *= alpha;
      float aj[4];
#pragma unroll
      for (int j = 0; j < 4; j++)
        aj[j] = __shfl(alpha, (lane & 48) + fq * 4 + j, 64);
#pragma unroll
      for (int df = 0; df < 4; df++)
#pragma unroll
        for (int j = 0; j < 4; j++) o[df][j] *= aj[j];
    }
    // P = exp2(S - mrun); per-lane partial row sum (reduced at flush)
#pragma unroll
    for (int kf = 0; kf < 4; kf++)
#pragma unroll
      for (int j = 0; j < 4; j++) {
        const float p = exp2_fast(sc[kf][j] - mrun);
        sc[kf][j] = p;
        lpart += p;
      }
    // P^T -> LDS [q][key] via packed bf16 pairs (keys consecutive)
    {
      u16* mypr = myp + fr * 72;
#pragma unroll
      for (int kf = 0; kf < 4; kf++) {
        const u32 p01 = cvt_pk2(sc[kf][0], sc[kf][1]);
        const u32 p23 = cvt_pk2(sc[kf][2], sc[kf][3]);
        *reinterpret_cast<u32*>(mypr + kf * 16 + fq * 4) = p01;
        *reinterpret_cast<u32*>(mypr + kf * 16 + fq * 4 + 2) = p23;
      }
    }
    bf16x8 pa[2];
#pragma unroll
    for (int kk = 0; kk < 2; kk++)
      pa[kk] = *reinterpret_cast<const bf16x8*>(myp + fr * 72 + kk * 32 + fq * 8);
    // O += P V  (unchanged: A = P rows from LDS, B = Vt tile)
    __builtin_amdgcn_s_setprio(1);
#pragma unroll
    for (int df = 0; df < 4; df++) {
#pragma unroll
      for (int kk = 0; kk < 2; kk++) {
        bf16x8 bv = *reinterpret_cast<const bf16x8*>(vb + offKV[df * 2 + kk]);
        o[df] = MFMA16(pa[kk], bv, o[df]);
      }
    }
    __builtin_amdgcn_s_setprio(0);

    const int nxt = ti + 2;
    if (nxt < nTot) {
      const int bufn = cur >= 1 ? cur - 1 : 2; // (cur+2)%3
      STAGE(bufn, KVIDX(nxt));
    }
    cur = cur == 2 ? 0 : cur + 1;
  }
  write_out(qtB);
#undef STAGE
#undef KVIDX
}

extern "C" void kernel_launch(void* const* d_in, const int* in_sizes, int n_in,
                              void* d_out, int out_size, void* d_ws, size_t ws_size,
                              hipStream_t stream) {
  const float* x = (const float*)d_in[0];
  const float* Wqkv = (const float*)d_in[1];
  const float* bqkv = (const float*)d_in[2];
  const float* Wout = (const float*)d_in[3];
  const float* bout = (const float*)d_in[4];
  float* out = (float*)d_out;

  char* p = (char*)d_ws;
  u16* xb = (u16*)p;    p += (size_t)MTOK * D * 2;       // 16.8 MB
  u16* wqkvT = (u16*)p; p += (size_t)3 * D * D * 2;      // 6.3 MB
  u16* woutT = (u16*)p; p += (size_t)D * D * 2;          // 2.1 MB
  u16* Qb = (u16*)p;    p += (size_t)BH * SS * HD * 2;   // 16.8 MB
  u16* Kb = (u16*)p;    p += (size_t)BH * SS * HD * 2;   // 16.8 MB
  u16* Vt = (u16*)p;    p += (size_t)BH * SS * HD * 2;   // 16.8 MB
  u16* vals = (u16*)p;  p += (size_t)MTOK * D * 2;       // 16.8 MB  (total ~92 MB)

  cvt_bf16<<<2048, 256, 0, stream>>>(x, xb, MTOK * D / 4);
  transpose_bf16<<<dim3(3 * D / 32, D / 32), dim3(32, 8), 0, stream>>>(Wqkv, wqkvT, D, 3 * D);
  transpose_bf16<<<dim3(D / 32, D / 32), dim3(32, 8), 0, stream>>>(Wout, woutT, D, D);
  gemm_bf16<0><<<dim3(MTOK / 128, 3 * D / 128), 256, 0, stream>>>(
      xb, wqkvT, bqkv, Qb, Kb, Vt, nullptr, MTOK, 3 * D, D);
  attn_fwd<<<dim3(512), 512, 0, stream>>>(Qb, Kb, Vt, vals);
  gemm_bf16<1><<<dim3(MTOK / 128, D / 128), 256, 0, stream>>>(
      vals, woutT, bout, nullptr, nullptr, nullptr, out, MTOK, D, D);
}